// Round 7
// baseline (500.901 us; speedup 1.0000x reference)
//
#include <hip/hip_runtime.h>
#include <hip/hip_bf16.h>

typedef __hip_bfloat16 bf16;
using f4 = __attribute__((ext_vector_type(4))) float;
using s8 = __attribute__((ext_vector_type(8))) short;

__device__ __forceinline__ void storeOut(float* p, float v) { *p = v; }
__device__ __forceinline__ void storeOut(bf16* p, float v) { *p = __float2bfloat16(v); }
__device__ __forceinline__ short bfs(float x) { return __builtin_bit_cast(short, __float2bfloat16(x)); }

constexpr int B_ = 4, T_ = 1024, M_ = 256, C_ = 512, H_ = 8, HD_ = 64, C3_ = 1536;

#define MFMA16(a, b, c) __builtin_amdgcn_mfma_f32_16x16x32_bf16((a), (b), (c), 0, 0, 0)

// ---------------- weight transpose + bf16 cast: W(K x N) -> WT(N x K) ----------------
__global__ __launch_bounds__(256) void transpose_w_kernel(
    const float* __restrict__ W, bf16* __restrict__ WT, int N, int K)
{
    __shared__ float Ls[64][65];
    const int tid = threadIdx.x;
    const int n0 = blockIdx.x * 64, k0 = blockIdx.y * 64;
    for (int t = tid; t < 1024; t += 256) {
        int kr = t >> 4, ng = t & 15;
        float4 v = *(const float4*)&W[(size_t)(k0 + kr) * N + n0 + ng * 4];
        Ls[ng * 4 + 0][kr] = v.x; Ls[ng * 4 + 1][kr] = v.y;
        Ls[ng * 4 + 2][kr] = v.z; Ls[ng * 4 + 3][kr] = v.w;
    }
    __syncthreads();
    for (int t = tid; t < 512; t += 256) {
        int n = t >> 3, kg = t & 7;
        s8 r;
        #pragma unroll
        for (int j = 0; j < 8; ++j) r[j] = bfs(Ls[n][kg * 8 + j]);
        *(s8*)&WT[(size_t)(n0 + n) * K + k0 + kg * 8] = r;
    }
}

// ---------------- fp32 -> bf16 convert (contiguous) ----------------
__global__ __launch_bounds__(256) void tobf16_kernel(
    const float* __restrict__ src, bf16* __restrict__ dst)
{
    int i = (blockIdx.x * 256 + threadIdx.x) * 8;
    s8 r;
    #pragma unroll
    for (int j = 0; j < 8; ++j) r[j] = bfs(src[i + j]);
    *(s8*)&dst[i] = r;
}

// ---------------- qw = bf16(q_x * w4xy), layout (B*T, C) ----------------
__global__ __launch_bounds__(256) void qw_kernel(
    const bf16* __restrict__ qkv_x, const float* __restrict__ w4xy, bf16* __restrict__ qw)
{
    int o = (blockIdx.x * 256 + threadIdx.x) * 8;
    int row = o >> 9, c = o & 511;
    const bf16* src = qkv_x + (size_t)row * C3_ + c;   // q part at offset 0, col c = h*64+d
    s8 r;
    #pragma unroll
    for (int j = 0; j < 8; ++j) r[j] = bfs(__bfloat162float(src[j]) * w4xy[c + j]);
    *(s8*)&qw[o] = r;
}

// ---------------- zero-LDS direct-fragment GEMM: C = A(MxK bf16) @ WT^T + bias ----------------
// grid (N/64, M/128); 4 waves; wave = 32 rows x 64 cols of 16x16x32 MFMA tiles.
// Frag layouts (verified R5/R6): A/B idx=lane&15, k=quad*8+j; C/D col=lane&15, row=quad*4+reg.
template <typename OT>
__global__ __launch_bounds__(256) void gemm_direct_kernel(
    const bf16* __restrict__ A, const bf16* __restrict__ WT, const float* __restrict__ bias,
    OT* __restrict__ Cmat, int N, int K)
{
    const int tid = threadIdx.x;
    const int wave = tid >> 6, lane = tid & 63;
    const int quad = lane >> 4, l16 = lane & 15;
    const int n0 = blockIdx.x * 64, m0 = blockIdx.y * 128;
    f4 acc[2][4];
    #pragma unroll
    for (int mt = 0; mt < 2; ++mt)
        #pragma unroll
        for (int nt = 0; nt < 4; ++nt) acc[mt][nt] = (f4)0.f;
    const bf16* a0p = A + (size_t)(m0 + wave * 32 + l16) * K + quad * 8;
    const bf16* a1p = a0p + (size_t)16 * K;
    const bf16* bp  = WT + (size_t)(n0 + l16) * K + quad * 8;
    #pragma unroll 4
    for (int k0 = 0; k0 < K; k0 += 32) {
        s8 a0 = *(const s8*)(a0p + k0);
        s8 a1 = *(const s8*)(a1p + k0);
        #pragma unroll
        for (int nt = 0; nt < 4; ++nt) {
            s8 bv = *(const s8*)(bp + (size_t)nt * 16 * K + k0);
            acc[0][nt] = MFMA16(a0, bv, acc[0][nt]);
            acc[1][nt] = MFMA16(a1, bv, acc[1][nt]);
        }
    }
    #pragma unroll
    for (int mt = 0; mt < 2; ++mt)
        #pragma unroll
        for (int nt = 0; nt < 4; ++nt) {
            int col = n0 + nt * 16 + l16;
            float bb = bias[col];
            #pragma unroll
            for (int reg = 0; reg < 4; ++reg) {
                int row = m0 + wave * 32 + mt * 16 + quad * 4 + reg;
                storeOut(&Cmat[(size_t)row * N + col], acc[mt][nt][reg] + bb);
            }
        }
}

// ---------------- catt1 / catt2 (bf16 qkv) ----------------
__global__ __launch_bounds__(256) void catt12_kernel(
    const bf16* __restrict__ qkv, const float* __restrict__ w4,
    float* __restrict__ out, int Nrows)
{
    int i = blockIdx.x * 256 + threadIdx.x;
    int bh = i / Nrows, t = i - bh * Nrows;
    int b = bh >> 3, h = bh & 7;
    const bf16* row = qkv + (size_t)(b * Nrows + t) * C3_ + h * HD_;
    const float* w = w4 + h * HD_;
    float s = 0.f;
    #pragma unroll
    for (int d = 0; d < HD_; ++d) s = fmaf(__bfloat162float(row[d]), w[d], s);
    out[i] = s;
}

// ---------------- catt = catt1 + catt2 + 0.125 * qw @ ky^T  [zero-LDS MFMA] ----------------
__global__ __launch_bounds__(256) void catt3_kernel(
    const bf16* __restrict__ qw, const bf16* __restrict__ qkv_y,
    const float* __restrict__ catt1, const float* __restrict__ catt2,
    float* __restrict__ catt)
{
    const int tid = threadIdx.x;
    const int wave = tid >> 6, lane = tid & 63;
    const int quad = lane >> 4, l16 = lane & 15;
    const int bh = blockIdx.z, b = bh >> 3, h = bh & 7;
    const int t0 = blockIdx.y * 64, m0 = blockIdx.x * 64;
    f4 sc[4];
    #pragma unroll
    for (int nt = 0; nt < 4; ++nt) sc[nt] = (f4)0.f;
    const bf16* ap = qw + (size_t)(b * T_ + t0 + wave * 16 + l16) * C_ + h * HD_ + quad * 8;
    const bf16* bp = qkv_y + (size_t)(b * M_ + m0 + l16) * C3_ + C_ + h * HD_ + quad * 8;
    #pragma unroll
    for (int k0 = 0; k0 < 64; k0 += 32) {
        s8 a = *(const s8*)(ap + k0);
        #pragma unroll
        for (int nt = 0; nt < 4; ++nt) {
            s8 bv = *(const s8*)(bp + (size_t)nt * 16 * C3_ + k0);
            sc[nt] = MFMA16(a, bv, sc[nt]);
        }
    }
    #pragma unroll
    for (int nt = 0; nt < 4; ++nt) {
        int m = m0 + nt * 16 + l16;
        float c2 = catt2[bh * M_ + m];
        #pragma unroll
        for (int reg = 0; reg < 4; ++reg) {
            int t = t0 + wave * 16 + quad * 4 + reg;
            catt[((size_t)bh * T_ + t) * M_ + m] =
                sc[nt][reg] * 0.125f + catt1[bh * T_ + t] + c2;
        }
    }
}

// ---------------- col softmax partial sums (no max — logits bounded) ----------------
__global__ __launch_bounds__(256) void colpart_kernel(
    const float* __restrict__ catt, float* __restrict__ psum)
{
    const int ch = blockIdx.x, bh = blockIdx.y, m = threadIdx.x;
    const float* p = catt + ((size_t)bh * T_ + ch * 64) * M_ + m;
    float s = 0.f;
    for (int t = 0; t < 64; ++t) s += __expf(p[t * M_]);
    psum[(bh * 16 + ch) * M_ + m] = s;
}

__global__ __launch_bounds__(256) void colfin_kernel(
    const float* __restrict__ psum, float* __restrict__ colinv)
{
    const int bh = blockIdx.x, m = threadIdx.x;
    float s = 0.f;
    #pragma unroll
    for (int ch = 0; ch < 16; ++ch) s += psum[(bh * 16 + ch) * M_ + m];
    colinv[bh * M_ + m] = 1.f / s;
}

// ---------------- fused row softmax -> x2y bf16  AND  y2x bf16 (one catt pass) ----------------
__global__ __launch_bounds__(256) void rowsoft_kernel(
    const float* __restrict__ catt, const float* __restrict__ colinv,
    bf16* __restrict__ x2y, bf16* __restrict__ y2x)
{
    const int wave = threadIdx.x >> 6, lane = threadIdx.x & 63;
    const int row = blockIdx.x * 4 + wave;     // < 32768
    const int bh = row >> 10;
    const float* p = catt + (size_t)row * M_;
    float e[4];
    float s = 0.f;
    #pragma unroll
    for (int j = 0; j < 4; ++j) { e[j] = __expf(p[j * 64 + lane]); s += e[j]; }
    for (int off = 1; off < 64; off <<= 1) s += __shfl_xor(s, off);
    float inv = 1.f / s;
    #pragma unroll
    for (int j = 0; j < 4; ++j) {
        int m = j * 64 + lane;
        x2y[(size_t)row * M_ + m] = __float2bfloat16(e[j] * inv);
        y2x[(size_t)row * M_ + m] = __float2bfloat16(e[j] * colinv[bh * M_ + m]);
    }
}

// ---------------- V transpose (bf16): qkv v-part -> vT[(bh), d, n] ----------------
__global__ __launch_bounds__(256) void vtrans_kernel(
    const bf16* __restrict__ qkv, bf16* __restrict__ vT, int Nrows)
{
    __shared__ short Ls[64][68];
    const int tid = threadIdx.x;
    const int bh = blockIdx.y, b = bh >> 3, h = bh & 7;
    const int t0 = blockIdx.x * 64;
    for (int i = tid; i < 4096; i += 256) {
        int tl = i >> 6, d = i & 63;
        Ls[d][tl] = __builtin_bit_cast(short,
            qkv[(size_t)(b * Nrows + t0 + tl) * C3_ + 2 * C_ + h * HD_ + d]);
    }
    __syncthreads();
    for (int i = tid; i < 4096; i += 256) {
        int d = i >> 6, tl = i & 63;
        vT[((size_t)bh * 64 + d) * Nrows + t0 + tl] = __builtin_bit_cast(bf16, Ls[d][tl]);
    }
}

// ---------------- cval = x + x2y @ v_y  [zero-LDS MFMA] ----------------
__global__ __launch_bounds__(256) void cval_kernel(
    const bf16* __restrict__ x2y, const bf16* __restrict__ vTy,
    const float* __restrict__ x, float* __restrict__ cval)
{
    const int tid = threadIdx.x;
    const int wave = tid >> 6, lane = tid & 63;
    const int quad = lane >> 4, l16 = lane & 15;
    const int bh = blockIdx.y, b = bh >> 3, h = bh & 7;
    const int t0 = blockIdx.x * 64;
    f4 o[4];
    #pragma unroll
    for (int dt = 0; dt < 4; ++dt) o[dt] = (f4)0.f;
    const bf16* ap = x2y + (size_t)(bh * T_ + t0 + wave * 16 + l16) * M_ + quad * 8;
    const bf16* bp = vTy + (size_t)(bh * 64 + l16) * M_ + quad * 8;
    #pragma unroll
    for (int k0 = 0; k0 < M_; k0 += 32) {
        s8 a = *(const s8*)(ap + k0);
        #pragma unroll
        for (int dt = 0; dt < 4; ++dt) {
            s8 bv = *(const s8*)(bp + (size_t)dt * 16 * M_ + k0);
            o[dt] = MFMA16(a, bv, o[dt]);
        }
    }
    #pragma unroll
    for (int reg = 0; reg < 4; ++reg) {
        int t = t0 + wave * 16 + quad * 4 + reg;
        #pragma unroll
        for (int dt = 0; dt < 4; ++dt) {
            size_t idx = (size_t)(b * T_ + t) * C_ + h * HD_ + dt * 16 + l16;
            cval[idx] = o[dt][reg] + x[idx];
        }
    }
}

// ---------------- zero-LDS flash attention (causal; no-max softmax, logits bounded) ----------------
// MODE 0: chain — Q=x2y, K=y2x (DK=256), V=vTx; out: cval += PV/l, cval_bf = bf16(cval)
// MODE 1: self  — Q=q_x, K=k_x from qkv_x_bf (DK=64), V=vTx; out: sval, sval_bf
// Q in registers; K/V fragments direct from global; only LDS = wave-private P transpose.
// NO __syncthreads in the whole kernel.
template <int MODE>
__global__ __launch_bounds__(256) void flash_direct_kernel(
    const bf16* __restrict__ Qsrc, const bf16* __restrict__ Ksrc,
    const bf16* __restrict__ vT, const bf16* __restrict__ qkv_x,
    float scale, float* __restrict__ outv, bf16* __restrict__ outbf)
{
    constexpr int NF = (MODE == 0) ? 8 : 2;    // Q fragments (DK/32)
    __shared__ short Ps[4][16][72];
    const int tid = threadIdx.x;
    const int wave = tid >> 6, lane = tid & 63;
    const int quad = lane >> 4, l16 = lane & 15;
    const int bh = blockIdx.y, b = bh >> 3, h = bh & 7;
    const int t0 = blockIdx.x * 64;

    s8 qf[NF];
    if constexpr (MODE == 0) {
        const bf16* qp = Qsrc + (size_t)(bh * T_ + t0 + wave * 16 + l16) * M_ + quad * 8;
        #pragma unroll
        for (int f = 0; f < 8; ++f) qf[f] = *(const s8*)(qp + f * 32);
    } else {
        const bf16* qp = qkv_x + (size_t)(b * T_ + t0 + wave * 16 + l16) * C3_ + h * HD_ + quad * 8;
        qf[0] = *(const s8*)qp;
        qf[1] = *(const s8*)(qp + 32);
    }

    f4 o[4];
    float lsum[4] = {0.f, 0.f, 0.f, 0.f};
    #pragma unroll
    for (int dt = 0; dt < 4; ++dt) o[dt] = (f4)0.f;

    const int nst = blockIdx.x + 1;
    for (int st = 0; st < nst; ++st) {
        const int s0 = st * 64;
        f4 sc[4];
        #pragma unroll
        for (int nt = 0; nt < 4; ++nt) sc[nt] = (f4)0.f;
        if constexpr (MODE == 0) {
            const bf16* kb = Ksrc + (size_t)(bh * T_ + s0 + l16) * M_ + quad * 8;
            #pragma unroll
            for (int f = 0; f < 8; ++f)
                #pragma unroll
                for (int nt = 0; nt < 4; ++nt) {
                    s8 bv = *(const s8*)(kb + (size_t)nt * 16 * M_ + f * 32);
                    sc[nt] = MFMA16(qf[f], bv, sc[nt]);
                }
        } else {
            const bf16* kb = qkv_x + (size_t)(b * T_ + s0 + l16) * C3_ + C_ + h * HD_ + quad * 8;
            #pragma unroll
            for (int f = 0; f < 2; ++f)
                #pragma unroll
                for (int nt = 0; nt < 4; ++nt) {
                    s8 bv = *(const s8*)(kb + (size_t)nt * 16 * C3_ + f * 32);
                    sc[nt] = MFMA16(qf[f], bv, sc[nt]);
                }
        }
        // mask + exp (no max-sub: logits bounded), accumulate l, stash P to wave-private LDS
        #pragma unroll
        for (int reg = 0; reg < 4; ++reg) {
            const int t_g = t0 + wave * 16 + quad * 4 + reg;
            #pragma unroll
            for (int nt = 0; nt < 4; ++nt) {
                float p = (s0 + nt * 16 + l16 <= t_g) ? __expf(sc[nt][reg] * scale) : 0.f;
                lsum[reg] += p;
                Ps[wave][quad * 4 + reg][nt * 16 + l16] = bfs(p);
            }
        }
        // PV (wave-internal lgkmcnt orders Ps write->read; no barrier)
        const bf16* vb = vT + (size_t)(bh * 64 + l16) * T_ + s0 + quad * 8;
        #pragma unroll
        for (int ks = 0; ks < 2; ++ks) {
            s8 a = *(const s8*)&Ps[wave][l16][ks * 32 + quad * 8];
            #pragma unroll
            for (int dt = 0; dt < 4; ++dt) {
                s8 bv = *(const s8*)(vb + (size_t)dt * 16 * T_ + ks * 32);
                o[dt] = MFMA16(a, bv, o[dt]);
            }
        }
    }
    #pragma unroll
    for (int reg = 0; reg < 4; ++reg) {
        float l = lsum[reg];
        l += __shfl_xor(l, 1); l += __shfl_xor(l, 2);
        l += __shfl_xor(l, 4); l += __shfl_xor(l, 8);
        const float inv = 1.f / l;
        const int t = t0 + wave * 16 + quad * 4 + reg;
        #pragma unroll
        for (int dt = 0; dt < 4; ++dt) {
            size_t idx = (size_t)(b * T_ + t) * C_ + h * HD_ + dt * 16 + l16;
            float v = o[dt][reg] * inv;
            if constexpr (MODE == 0) v += outv[idx];
            outv[idx] = v;
            outbf[idx] = __float2bfloat16(v);
        }
    }
}

// ---------------- gating elementwise -> gated bf16 ----------------
__global__ __launch_bounds__(256) void gate_kernel(
    const float* __restrict__ gs_lin, const float* __restrict__ gc_lin,
    const float* __restrict__ cval, const float* __restrict__ sval,
    bf16* __restrict__ gated)
{
    int i = blockIdx.x * 256 + threadIdx.x;
    float sg = 1.f / (1.f + __expf(-gs_lin[i]));
    float cg = 1.f / (1.f + __expf(-gc_lin[i]));
    gated[i] = __float2bfloat16(sg * cval[i] + cg * sval[i]);
}

extern "C" void kernel_launch(void* const* d_in, const int* in_sizes, int n_in,
                              void* d_out, int out_size, void* d_ws, size_t ws_size,
                              hipStream_t stream)
{
    const float* x      = (const float*)d_in[0];
    const float* y      = (const float*)d_in[1];
    // d_in[2]: attn_x_mask — structurally causal tril, computed inline
    const float* Wqkv_x = (const float*)d_in[3];
    const float* bqkv_x = (const float*)d_in[4];
    const float* Wqkv_y = (const float*)d_in[5];
    const float* bqkv_y = (const float*)d_in[6];
    const float* w4x    = (const float*)d_in[7];
    const float* w4y    = (const float*)d_in[8];
    const float* w4xy   = (const float*)d_in[9];
    const float* Wgs    = (const float*)d_in[10];
    const float* bgs    = (const float*)d_in[11];
    const float* Wgc    = (const float*)d_in[12];
    const float* bgc    = (const float*)d_in[13];
    const float* Wp     = (const float*)d_in[14];
    const float* bp     = (const float*)d_in[15];

    // Workspace layout (f-word offsets; total 113.97 MB <= proven 115.6 MB)
    float* ws = (float*)d_ws;
    bf16*  qkv_x_bf = (bf16*)(ws + 0);           // 6,291,456 bf16
    bf16*  qkv_y_bf = (bf16*)(ws + 3145728);     // 1,572,864 bf16
    float* catt     = ws + 3932160;              // 8,388,608 f (dead after rowsoft)
    float* gs_lin   = ws + 3932160;              //   reuse: 2,097,152 f
    float* gc_lin   = ws + 6029312;              //   reuse: 2,097,152 f
    bf16*  gated_bf = (bf16*)(ws + 8126464);     //   reuse: 2,097,152 bf16
    bf16*  cval_bf  = (bf16*)(ws + 9175040);     //   reuse: 2,097,152 bf16
    bf16*  x2y_bf   = (bf16*)(ws + 12320768);    // 8,388,608 bf16 (written at rowsoft)
    bf16*  x_bf     = x2y_bf;                    //   pre-QKV reuse: 2,097,152 bf16
    bf16*  y_bf     = (bf16*)(ws + 13369344);    //   pre-QKV reuse: 524,288 bf16
    bf16*  y2x_bf   = (bf16*)(ws + 16515072);    // 8,388,608 bf16
    bf16*  vTx_bf   = (bf16*)(ws + 20709376);    // 2,097,152 bf16
    bf16*  vTy_bf   = (bf16*)(ws + 21757952);    // 524,288 bf16
    float* cval     = ws + 22020096;             // 2,097,152 f
    float* psum_    = cval;                      //   pre-cval reuse: 131,072 f
    float* sval     = ws + 24117248;             // 2,097,152 f
    bf16*  qw_bf    = (bf16*)(ws + 26214400);    // 2,097,152 bf16 (dead after catt3)
    bf16*  sval_bf  = qw_bf;                     //   reuse
    bf16*  WT_x     = (bf16*)(ws + 27262976);    // 786,432 bf16
    bf16*  WT_y     = (bf16*)(ws + 27656192);    // 786,432 bf16
    bf16*  WT_gs    = (bf16*)(ws + 28049408);    // 262,144 bf16
    bf16*  WT_gc    = (bf16*)(ws + 28180480);
    bf16*  WT_p     = (bf16*)(ws + 28311552);
    float* catt1b   = ws + 28442624;             // 32,768 f
    float* catt2b   = ws + 28475392;             //  8,192 f
    float* colinv   = ws + 28483584;             //  8,192 f

    // 0: weight transposes + input converts
    transpose_w_kernel<<<dim3(24, 8), 256, 0, stream>>>(Wqkv_x, WT_x, C3_, C_);
    transpose_w_kernel<<<dim3(24, 8), 256, 0, stream>>>(Wqkv_y, WT_y, C3_, C_);
    transpose_w_kernel<<<dim3(8, 8), 256, 0, stream>>>(Wgs, WT_gs, C_, C_);
    transpose_w_kernel<<<dim3(8, 8), 256, 0, stream>>>(Wgc, WT_gc, C_, C_);
    transpose_w_kernel<<<dim3(8, 8), 256, 0, stream>>>(Wp, WT_p, C_, C_);
    tobf16_kernel<<<1024, 256, 0, stream>>>(x, x_bf);
    tobf16_kernel<<<256, 256, 0, stream>>>(y, y_bf);

    // 1-2: QKV projections (bf16 out)
    gemm_direct_kernel<bf16><<<dim3(24, 32), 256, 0, stream>>>(x_bf, WT_x, bqkv_x, qkv_x_bf, C3_, C_);
    gemm_direct_kernel<bf16><<<dim3(24, 8), 256, 0, stream>>>(y_bf, WT_y, bqkv_y, qkv_y_bf, C3_, C_);

    // 3-5: attention logits catt (B,H,T,M)
    catt12_kernel<<<128, 256, 0, stream>>>(qkv_x_bf, w4x, catt1b, T_);
    catt12_kernel<<<32, 256, 0, stream>>>(qkv_y_bf, w4y, catt2b, M_);
    qw_kernel<<<1024, 256, 0, stream>>>(qkv_x_bf, w4xy, qw_bf);
    catt3_kernel<<<dim3(4, 16, 32), 256, 0, stream>>>(qw_bf, qkv_y_bf, catt1b, catt2b, catt);

    // 6: column softmax sums -> colinv; 7: fused row softmax -> x2y & y2x (one catt pass)
    colpart_kernel<<<dim3(16, 32), 256, 0, stream>>>(catt, psum_);
    colfin_kernel<<<32, 256, 0, stream>>>(psum_, colinv);
    rowsoft_kernel<<<8192, 256, 0, stream>>>(catt, colinv, x2y_bf, y2x_bf);

    // 8: V transposes
    vtrans_kernel<<<dim3(16, 32), 256, 0, stream>>>(qkv_x_bf, vTx_bf, T_);
    vtrans_kernel<<<dim3(4, 32), 256, 0, stream>>>(qkv_y_bf, vTy_bf, M_);

    // 9: cval = x + x2y @ v_y
    cval_kernel<<<dim3(16, 32), 256, 0, stream>>>(x2y_bf, vTy_bf, x, cval);

    // 10: cval += chain-attention; cval_bf = bf16(cval)
    flash_direct_kernel<0><<<dim3(16, 32), 256, 0, stream>>>(
        x2y_bf, y2x_bf, vTx_bf, qkv_x_bf, 1.f / 16.f, cval, cval_bf);

    // 11: sval = causal self-attention
    flash_direct_kernel<1><<<dim3(16, 32), 256, 0, stream>>>(
        nullptr, nullptr, vTx_bf, qkv_x_bf, 0.125f, sval, sval_bf);

    // 12-15: gates and output projection
    gemm_direct_kernel<float><<<dim3(8, 32), 256, 0, stream>>>(sval_bf, WT_gs, bgs, gs_lin, C_, C_);
    gemm_direct_kernel<float><<<dim3(8, 32), 256, 0, stream>>>(cval_bf, WT_gc, bgc, gc_lin, C_, C_);
    gate_kernel<<<8192, 256, 0, stream>>>(gs_lin, gc_lin, cval, sval, gated_bf);
    gemm_direct_kernel<float><<<dim3(8, 32), 256, 0, stream>>>(gated_bf, WT_p, bp, (float*)d_out, C_, C_);
}

// Round 8
// 306.704 us; speedup vs baseline: 1.6332x; 1.6332x over previous
//
#include <hip/hip_runtime.h>
#include <hip/hip_bf16.h>

typedef __hip_bfloat16 bf16;
using f4 = __attribute__((ext_vector_type(4))) float;
using s8 = __attribute__((ext_vector_type(8))) short;

__device__ __forceinline__ void storeOut(float* p, float v) { *p = v; }
__device__ __forceinline__ void storeOut(bf16* p, float v) { *p = __float2bfloat16(v); }
__device__ __forceinline__ short bfs(float x) { return __builtin_bit_cast(short, __float2bfloat16(x)); }

constexpr int B_ = 4, T_ = 1024, M_ = 256, C_ = 512, H_ = 8, HD_ = 64, C3_ = 1536;

#define MFMA16(a, b, c) __builtin_amdgcn_mfma_f32_16x16x32_bf16((a), (b), (c), 0, 0, 0)

// ---------------- weight transpose + bf16 cast: W(K x N) -> WT(N x K) ----------------
__global__ __launch_bounds__(256) void transpose_w_kernel(
    const float* __restrict__ W, bf16* __restrict__ WT, int N, int K)
{
    __shared__ float Ls[64][65];
    const int tid = threadIdx.x;
    const int n0 = blockIdx.x * 64, k0 = blockIdx.y * 64;
    for (int t = tid; t < 1024; t += 256) {
        int kr = t >> 4, ng = t & 15;
        float4 v = *(const float4*)&W[(size_t)(k0 + kr) * N + n0 + ng * 4];
        Ls[ng * 4 + 0][kr] = v.x; Ls[ng * 4 + 1][kr] = v.y;
        Ls[ng * 4 + 2][kr] = v.z; Ls[ng * 4 + 3][kr] = v.w;
    }
    __syncthreads();
    for (int t = tid; t < 512; t += 256) {
        int n = t >> 3, kg = t & 7;
        s8 r;
        #pragma unroll
        for (int j = 0; j < 8; ++j) r[j] = bfs(Ls[n][kg * 8 + j]);
        *(s8*)&WT[(size_t)(n0 + n) * K + k0 + kg * 8] = r;
    }
}

// ---------------- fp32 -> bf16 convert (contiguous) ----------------
__global__ __launch_bounds__(256) void tobf16_kernel(
    const float* __restrict__ src, bf16* __restrict__ dst)
{
    int i = (blockIdx.x * 256 + threadIdx.x) * 8;
    s8 r;
    #pragma unroll
    for (int j = 0; j < 8; ++j) r[j] = bfs(src[i + j]);
    *(s8*)&dst[i] = r;
}

// ---------------- qw = bf16(q_x * w4xy), layout (B*T, C) ----------------
__global__ __launch_bounds__(256) void qw_kernel(
    const bf16* __restrict__ qkv_x, const float* __restrict__ w4xy, bf16* __restrict__ qw)
{
    int o = (blockIdx.x * 256 + threadIdx.x) * 8;
    int row = o >> 9, c = o & 511;
    const bf16* src = qkv_x + (size_t)row * C3_ + c;
    s8 r;
    #pragma unroll
    for (int j = 0; j < 8; ++j) r[j] = bfs(__bfloat162float(src[j]) * w4xy[c + j]);
    *(s8*)&qw[o] = r;
}

// ---------------- LDS-staged MFMA GEMM: C = A(MxK bf16) @ WT^T + bias ----------------
// 128x64 tile, BK=64; frag layouts verified R5-R7.
template <typename OT>
__global__ __launch_bounds__(256) void gemm_staged_kernel(
    const bf16* __restrict__ A, const bf16* __restrict__ WT, const float* __restrict__ bias,
    OT* __restrict__ Cmat, int N, int K)
{
    __shared__ short Asb[128][72];
    __shared__ short Bsb[64][72];
    const int tid = threadIdx.x;
    const int wave = tid >> 6, lane = tid & 63;
    const int quad = lane >> 4, l16 = lane & 15;
    const int n0 = blockIdx.x * 64, m0 = blockIdx.y * 128;
    f4 acc[2][4];
    #pragma unroll
    for (int mt = 0; mt < 2; ++mt)
        #pragma unroll
        for (int nt = 0; nt < 4; ++nt) acc[mt][nt] = (f4)0.f;

    for (int k0 = 0; k0 < K; k0 += 64) {
        #pragma unroll
        for (int tl = 0; tl < 4; ++tl) {
            int g = tid + tl * 256, row = g >> 3, grp = g & 7;
            *(s8*)&Asb[row][grp * 8] = *(const s8*)&A[(size_t)(m0 + row) * K + k0 + grp * 8];
        }
        #pragma unroll
        for (int tl = 0; tl < 2; ++tl) {
            int g = tid + tl * 256, n = g >> 3, grp = g & 7;
            *(s8*)&Bsb[n][grp * 8] = *(const s8*)&WT[(size_t)(n0 + n) * K + k0 + grp * 8];
        }
        __syncthreads();
        #pragma unroll
        for (int ks = 0; ks < 2; ++ks) {
            s8 a0 = *(const s8*)&Asb[wave * 32 + l16][ks * 32 + quad * 8];
            s8 a1 = *(const s8*)&Asb[wave * 32 + 16 + l16][ks * 32 + quad * 8];
            #pragma unroll
            for (int nt = 0; nt < 4; ++nt) {
                s8 bv = *(const s8*)&Bsb[nt * 16 + l16][ks * 32 + quad * 8];
                acc[0][nt] = MFMA16(a0, bv, acc[0][nt]);
                acc[1][nt] = MFMA16(a1, bv, acc[1][nt]);
            }
        }
        __syncthreads();
    }
    #pragma unroll
    for (int mt = 0; mt < 2; ++mt)
        #pragma unroll
        for (int nt = 0; nt < 4; ++nt) {
            int col = n0 + nt * 16 + l16;
            float bb = bias[col];
            #pragma unroll
            for (int reg = 0; reg < 4; ++reg) {
                int row = m0 + wave * 32 + mt * 16 + quad * 4 + reg;
                storeOut(&Cmat[(size_t)row * N + col], acc[mt][nt][reg] + bb);
            }
        }
}

// ---------------- catt1 / catt2 ----------------
__global__ __launch_bounds__(256) void catt12_kernel(
    const bf16* __restrict__ qkv, const float* __restrict__ w4,
    float* __restrict__ out, int Nrows)
{
    int i = blockIdx.x * 256 + threadIdx.x;
    int bh = i / Nrows, t = i - bh * Nrows;
    int b = bh >> 3, h = bh & 7;
    const bf16* row = qkv + (size_t)(b * Nrows + t) * C3_ + h * HD_;
    const float* w = w4 + h * HD_;
    float s = 0.f;
    #pragma unroll
    for (int d = 0; d < HD_; ++d) s = fmaf(__bfloat162float(row[d]), w[d], s);
    out[i] = s;
}

// ---------------- catt = catt1 + catt2 + 0.125 * qw @ ky^T  [zero-LDS MFMA] ----------------
__global__ __launch_bounds__(256) void catt3_kernel(
    const bf16* __restrict__ qw, const bf16* __restrict__ qkv_y,
    const float* __restrict__ catt1, const float* __restrict__ catt2,
    float* __restrict__ catt)
{
    const int tid = threadIdx.x;
    const int wave = tid >> 6, lane = tid & 63;
    const int quad = lane >> 4, l16 = lane & 15;
    const int bh = blockIdx.z, b = bh >> 3, h = bh & 7;
    const int t0 = blockIdx.y * 64, m0 = blockIdx.x * 64;
    f4 sc[4];
    #pragma unroll
    for (int nt = 0; nt < 4; ++nt) sc[nt] = (f4)0.f;
    const bf16* ap = qw + (size_t)(b * T_ + t0 + wave * 16 + l16) * C_ + h * HD_ + quad * 8;
    const bf16* bp = qkv_y + (size_t)(b * M_ + m0 + l16) * C3_ + C_ + h * HD_ + quad * 8;
    #pragma unroll
    for (int k0 = 0; k0 < 64; k0 += 32) {
        s8 a = *(const s8*)(ap + k0);
        #pragma unroll
        for (int nt = 0; nt < 4; ++nt) {
            s8 bv = *(const s8*)(bp + (size_t)nt * 16 * C3_ + k0);
            sc[nt] = MFMA16(a, bv, sc[nt]);
        }
    }
    #pragma unroll
    for (int nt = 0; nt < 4; ++nt) {
        int m = m0 + nt * 16 + l16;
        float c2 = catt2[bh * M_ + m];
        #pragma unroll
        for (int reg = 0; reg < 4; ++reg) {
            int t = t0 + wave * 16 + quad * 4 + reg;
            catt[((size_t)bh * T_ + t) * M_ + m] =
                sc[nt][reg] * 0.125f + catt1[bh * T_ + t] + c2;
        }
    }
}

// ---------------- col softmax sums (no max — logits bounded) ----------------
__global__ __launch_bounds__(256) void colpart_kernel(
    const float* __restrict__ catt, float* __restrict__ psum)
{
    const int ch = blockIdx.x, bh = blockIdx.y, m = threadIdx.x;
    const float* p = catt + ((size_t)bh * T_ + ch * 64) * M_ + m;
    float s = 0.f;
    for (int t = 0; t < 64; ++t) s += __expf(p[t * M_]);
    psum[(bh * 16 + ch) * M_ + m] = s;
}

__global__ __launch_bounds__(256) void colfin_kernel(
    const float* __restrict__ psum, float* __restrict__ colinv)
{
    const int bh = blockIdx.x, m = threadIdx.x;
    float s = 0.f;
    #pragma unroll
    for (int ch = 0; ch < 16; ++ch) s += psum[(bh * 16 + ch) * M_ + m];
    colinv[bh * M_ + m] = 1.f / s;
}

// ---------------- fused row softmax -> x2y bf16 AND y2x bf16 ----------------
__global__ __launch_bounds__(256) void rowsoft_kernel(
    const float* __restrict__ catt, const float* __restrict__ colinv,
    bf16* __restrict__ x2y, bf16* __restrict__ y2x)
{
    const int wave = threadIdx.x >> 6, lane = threadIdx.x & 63;
    const int row = blockIdx.x * 4 + wave;
    const int bh = row >> 10;
    const float* p = catt + (size_t)row * M_;
    float e[4];
    float s = 0.f;
    #pragma unroll
    for (int j = 0; j < 4; ++j) { e[j] = __expf(p[j * 64 + lane]); s += e[j]; }
    for (int off = 1; off < 64; off <<= 1) s += __shfl_xor(s, off);
    float inv = 1.f / s;
    #pragma unroll
    for (int j = 0; j < 4; ++j) {
        int m = j * 64 + lane;
        x2y[(size_t)row * M_ + m] = __float2bfloat16(e[j] * inv);
        y2x[(size_t)row * M_ + m] = __float2bfloat16(e[j] * colinv[bh * M_ + m]);
    }
}

// ---------------- V transpose (bf16): qkv v-part -> vT[(bh), d, n] ----------------
__global__ __launch_bounds__(256) void vtrans_kernel(
    const bf16* __restrict__ qkv, bf16* __restrict__ vT, int Nrows)
{
    __shared__ short Ls[64][68];
    const int tid = threadIdx.x;
    const int bh = blockIdx.y, b = bh >> 3, h = bh & 7;
    const int t0 = blockIdx.x * 64;
    for (int i = tid; i < 4096; i += 256) {
        int tl = i >> 6, d = i & 63;
        Ls[d][tl] = __builtin_bit_cast(short,
            qkv[(size_t)(b * Nrows + t0 + tl) * C3_ + 2 * C_ + h * HD_ + d]);
    }
    __syncthreads();
    for (int i = tid; i < 4096; i += 256) {
        int d = i >> 6, tl = i & 63;
        vT[((size_t)bh * 64 + d) * Nrows + t0 + tl] = __builtin_bit_cast(bf16, Ls[d][tl]);
    }
}

// ---------------- staged double-buffered flash (causal; no-max softmax) ----------------
// MODE 0: chain — Q=x2y (regs), K=y2x, V=vTx; FUSED cval: ocv = x2y @ vTy;
//         out: cval = x + ocv + PV/l (fp32 + bf16)
// MODE 1: self  — Q=q_x, K=k_x, V=vTx; out: sval (fp32 + bf16)
// One __syncthreads per key tile; K/V staged coalesced, prefetched to VGPRs.
template <int MODE>
__global__ __launch_bounds__(256) void flash2_kernel(
    const bf16* __restrict__ Qsrc, const bf16* __restrict__ Ksrc,
    const bf16* __restrict__ vT, const bf16* __restrict__ vTy,
    const bf16* __restrict__ qkv_x, const float* __restrict__ x,
    float scale, float* __restrict__ outv, bf16* __restrict__ outbf)
{
    constexpr int DK = (MODE == 0) ? 256 : 64;
    constexpr int NF = DK / 32;            // Q fragments per wave
    constexpr int NKP = (MODE == 0) ? 8 : 2; // K staging s8 per thread
    __shared__ short Kb[2][64][DK + 8];
    __shared__ short Vb[2][64][72];
    __shared__ short Ps[4][16][72];
    const int tid = threadIdx.x;
    const int wave = tid >> 6, lane = tid & 63;
    const int quad = lane >> 4, l16 = lane & 15;
    const int bh = blockIdx.y, b = bh >> 3, h = bh & 7;
    const int t0 = blockIdx.x * 64;
    const int nst = blockIdx.x + 1;

    // Q fragments in registers (one-time, latency amortized)
    s8 qf[NF];
    if constexpr (MODE == 0) {
        const bf16* qp = Qsrc + (size_t)(bh * T_ + t0 + wave * 16 + l16) * M_ + quad * 8;
        #pragma unroll
        for (int f = 0; f < NF; ++f) qf[f] = *(const s8*)(qp + f * 32);
    } else {
        const bf16* qp = qkv_x + (size_t)(b * T_ + t0 + wave * 16 + l16) * C3_ + h * HD_ + quad * 8;
        #pragma unroll
        for (int f = 0; f < NF; ++f) qf[f] = *(const s8*)(qp + f * 32);
    }

    f4 o[4];
    float lsum[4] = {0.f, 0.f, 0.f, 0.f};
    #pragma unroll
    for (int dt = 0; dt < 4; ++dt) o[dt] = (f4)0.f;

    f4 ocv[4];
    if constexpr (MODE == 0) {
        #pragma unroll
        for (int dt = 0; dt < 4; ++dt) ocv[dt] = (f4)0.f;
        // fused cval: x2y(regs) @ vTy, K=256 over m (direct frags, once per block)
        const bf16* vb = vTy + (size_t)(bh * 64 + l16) * M_ + quad * 8;
        #pragma unroll
        for (int f = 0; f < NF; ++f)
            #pragma unroll
            for (int dt = 0; dt < 4; ++dt) {
                s8 bv = *(const s8*)(vb + (size_t)dt * 16 * M_ + f * 32);
                ocv[dt] = MFMA16(qf[f], bv, ocv[dt]);
            }
    }

    // prologue: stage tile 0 into buffer 0 (coalesced: lanes -> consecutive 16B)
    if constexpr (MODE == 0) {
        #pragma unroll
        for (int tl = 0; tl < 8; ++tl) {
            int g = tid + tl * 256, row = g >> 5, grp = g & 31;
            *(s8*)&Kb[0][row][grp * 8] = *(const s8*)&Ksrc[(size_t)(bh * T_ + row) * M_ + grp * 8];
        }
    } else {
        #pragma unroll
        for (int tl = 0; tl < 2; ++tl) {
            int g = tid + tl * 256, row = g >> 3, grp = g & 7;
            *(s8*)&Kb[0][row][grp * 8] =
                *(const s8*)&qkv_x[(size_t)(b * T_ + row) * C3_ + C_ + h * HD_ + grp * 8];
        }
    }
    #pragma unroll
    for (int tl = 0; tl < 2; ++tl) {
        int g = tid + tl * 256, d = g >> 3, grp = g & 7;
        *(s8*)&Vb[0][d][grp * 8] = *(const s8*)&vT[(size_t)(bh * 64 + d) * T_ + grp * 8];
    }
    __syncthreads();

    for (int st = 0; st < nst; ++st) {
        const int cur = st & 1;
        const int s0 = st * 64;
        const bool pf = (st + 1) < nst;
        s8 kpre[NKP], vpre[2];
        if (pf) {
            const int sn = s0 + 64;
            if constexpr (MODE == 0) {
                #pragma unroll
                for (int tl = 0; tl < 8; ++tl) {
                    int g = tid + tl * 256, row = g >> 5, grp = g & 31;
                    kpre[tl] = *(const s8*)&Ksrc[(size_t)(bh * T_ + sn + row) * M_ + grp * 8];
                }
            } else {
                #pragma unroll
                for (int tl = 0; tl < 2; ++tl) {
                    int g = tid + tl * 256, row = g >> 3, grp = g & 7;
                    kpre[tl] = *(const s8*)&qkv_x[(size_t)(b * T_ + sn + row) * C3_ + C_ + h * HD_ + grp * 8];
                }
            }
            #pragma unroll
            for (int tl = 0; tl < 2; ++tl) {
                int g = tid + tl * 256, d = g >> 3, grp = g & 7;
                vpre[tl] = *(const s8*)&vT[(size_t)(bh * 64 + d) * T_ + sn + grp * 8];
            }
        }
        // QK^T from LDS (2-way-only bank pattern: row pad 16B)
        f4 sc[4];
        #pragma unroll
        for (int nt = 0; nt < 4; ++nt) sc[nt] = (f4)0.f;
        #pragma unroll
        for (int f = 0; f < NF; ++f)
            #pragma unroll
            for (int nt = 0; nt < 4; ++nt) {
                s8 bv = *(const s8*)&Kb[cur][nt * 16 + l16][f * 32 + quad * 8];
                sc[nt] = MFMA16(qf[f], bv, sc[nt]);
            }
        // mask + exp (no max-sub), accumulate l, P -> wave-private LDS
        #pragma unroll
        for (int reg = 0; reg < 4; ++reg) {
            const int t_g = t0 + wave * 16 + quad * 4 + reg;
            #pragma unroll
            for (int nt = 0; nt < 4; ++nt) {
                float p = (s0 + nt * 16 + l16 <= t_g) ? __expf(sc[nt][reg] * scale) : 0.f;
                lsum[reg] += p;
                Ps[wave][quad * 4 + reg][nt * 16 + l16] = bfs(p);
            }
        }
        // PV from LDS (wave-internal ordering; no barrier)
        #pragma unroll
        for (int ks = 0; ks < 2; ++ks) {
            s8 a = *(const s8*)&Ps[wave][l16][ks * 32 + quad * 8];
            #pragma unroll
            for (int dt = 0; dt < 4; ++dt) {
                s8 bv = *(const s8*)&Vb[cur][dt * 16 + l16][ks * 32 + quad * 8];
                o[dt] = MFMA16(a, bv, o[dt]);
            }
        }
        // commit prefetch to the other buffer, single barrier
        if (pf) {
            const int nxt = cur ^ 1;
            if constexpr (MODE == 0) {
                #pragma unroll
                for (int tl = 0; tl < 8; ++tl) {
                    int g = tid + tl * 256, row = g >> 5, grp = g & 31;
                    *(s8*)&Kb[nxt][row][grp * 8] = kpre[tl];
                }
            } else {
                #pragma unroll
                for (int tl = 0; tl < 2; ++tl) {
                    int g = tid + tl * 256, row = g >> 3, grp = g & 7;
                    *(s8*)&Kb[nxt][row][grp * 8] = kpre[tl];
                }
            }
            #pragma unroll
            for (int tl = 0; tl < 2; ++tl) {
                int g = tid + tl * 256, d = g >> 3, grp = g & 7;
                *(s8*)&Vb[nxt][d][grp * 8] = vpre[tl];
            }
        }
        __syncthreads();
    }

    #pragma unroll
    for (int reg = 0; reg < 4; ++reg) {
        float l = lsum[reg];
        l += __shfl_xor(l, 1); l += __shfl_xor(l, 2);
        l += __shfl_xor(l, 4); l += __shfl_xor(l, 8);
        const float inv = 1.f / l;
        const int t = t0 + wave * 16 + quad * 4 + reg;
        #pragma unroll
        for (int dt = 0; dt < 4; ++dt) {
            size_t idx = (size_t)(b * T_ + t) * C_ + h * HD_ + dt * 16 + l16;
            float v;
            if constexpr (MODE == 0) v = ocv[dt][reg] + o[dt][reg] * inv + x[idx];
            else                     v = o[dt][reg] * inv;
            outv[idx] = v;
            outbf[idx] = __float2bfloat16(v);
        }
    }
}

// ---------------- fused dual gate GEMM + sigmoid + combine -> gated bf16 ----------------
// gated = sig(sval@Wgs+bgs)*cval + sig(cval@Wgc+bgc)*sval
__global__ __launch_bounds__(256) void gatefuse_kernel(
    const bf16* __restrict__ svalb, const bf16* __restrict__ cvalb,
    const bf16* __restrict__ WTgs, const bf16* __restrict__ WTgc,
    const float* __restrict__ bgs, const float* __restrict__ bgc,
    const float* __restrict__ cval, const float* __restrict__ sval,
    bf16* __restrict__ gated)
{
    __shared__ short Sb[128][72], Cb[128][72], W1b[64][72], W2b[64][72];
    const int tid = threadIdx.x;
    const int wave = tid >> 6, lane = tid & 63;
    const int quad = lane >> 4, l16 = lane & 15;
    const int n0 = blockIdx.x * 64, m0 = blockIdx.y * 128;
    f4 aS[2][4], aC[2][4];
    #pragma unroll
    for (int mt = 0; mt < 2; ++mt)
        #pragma unroll
        for (int nt = 0; nt < 4; ++nt) { aS[mt][nt] = (f4)0.f; aC[mt][nt] = (f4)0.f; }

    for (int k0 = 0; k0 < C_; k0 += 64) {
        #pragma unroll
        for (int tl = 0; tl < 4; ++tl) {
            int g = tid + tl * 256, row = g >> 3, grp = g & 7;
            *(s8*)&Sb[row][grp * 8] = *(const s8*)&svalb[(size_t)(m0 + row) * C_ + k0 + grp * 8];
            *(s8*)&Cb[row][grp * 8] = *(const s8*)&cvalb[(size_t)(m0 + row) * C_ + k0 + grp * 8];
        }
        #pragma unroll
        for (int tl = 0; tl < 2; ++tl) {
            int g = tid + tl * 256, n = g >> 3, grp = g & 7;
            *(s8*)&W1b[n][grp * 8] = *(const s8*)&WTgs[(size_t)(n0 + n) * C_ + k0 + grp * 8];
            *(s8*)&W2b[n][grp * 8] = *(const s8*)&WTgc[(size_t)(n0 + n) * C_ + k0 + grp * 8];
        }
        __syncthreads();
        #pragma unroll
        for (int ks = 0; ks < 2; ++ks) {
            s8 s0f = *(const s8*)&Sb[wave * 32 + l16][ks * 32 + quad * 8];
            s8 s1f = *(const s8*)&Sb[wave * 32 + 16 + l16][ks * 32 + quad * 8];
            s8 c0f = *(const s8*)&Cb[wave * 32 + l16][ks * 32 + quad * 8];
            s8 c1f = *(const s8*)&Cb[wave * 32 + 16 + l16][ks * 32 + quad * 8];
            #pragma unroll
            for (int nt = 0; nt < 4; ++nt) {
                s8 w1 = *(const s8*)&W1b[nt * 16 + l16][ks * 32 + quad * 8];
                s8 w2 = *(const s8*)&W2b[nt * 16 + l16][ks * 32 + quad * 8];
                aS[0][nt] = MFMA16(s0f, w1, aS[0][nt]);
                aS[1][nt] = MFMA16(s1f, w1, aS[1][nt]);
                aC[0][nt] = MFMA16(c0f, w2, aC[0][nt]);
                aC[1][nt] = MFMA16(c1f, w2, aC[1][nt]);
            }
        }
        __syncthreads();
    }
    #pragma unroll
    for (int mt = 0; mt < 2; ++mt)
        #pragma unroll
        for (int nt = 0; nt < 4; ++nt) {
            int col = n0 + nt * 16 + l16;
            float b1 = bgs[col], b2 = bgc[col];
            #pragma unroll
            for (int reg = 0; reg < 4; ++reg) {
                int row = m0 + wave * 32 + mt * 16 + quad * 4 + reg;
                size_t idx = (size_t)row * C_ + col;
                float gs = 1.f / (1.f + __expf(-(aS[mt][nt][reg] + b1)));
                float gc = 1.f / (1.f + __expf(-(aC[mt][nt][reg] + b2)));
                gated[idx] = __float2bfloat16(gs * cval[idx] + gc * sval[idx]);
            }
        }
}

extern "C" void kernel_launch(void* const* d_in, const int* in_sizes, int n_in,
                              void* d_out, int out_size, void* d_ws, size_t ws_size,
                              hipStream_t stream)
{
    const float* x      = (const float*)d_in[0];
    const float* y      = (const float*)d_in[1];
    // d_in[2]: attn_x_mask — structurally causal tril, computed inline
    const float* Wqkv_x = (const float*)d_in[3];
    const float* bqkv_x = (const float*)d_in[4];
    const float* Wqkv_y = (const float*)d_in[5];
    const float* bqkv_y = (const float*)d_in[6];
    const float* w4x    = (const float*)d_in[7];
    const float* w4y    = (const float*)d_in[8];
    const float* w4xy   = (const float*)d_in[9];
    const float* Wgs    = (const float*)d_in[10];
    const float* bgs    = (const float*)d_in[11];
    const float* Wgc    = (const float*)d_in[12];
    const float* bgc    = (const float*)d_in[13];
    const float* Wp     = (const float*)d_in[14];
    const float* bp     = (const float*)d_in[15];

    // Workspace (f-word offsets; total ~114.0 MB, within the R4-proven budget)
    float* ws = (float*)d_ws;
    bf16*  qkv_x_bf = (bf16*)(ws + 0);           // 6,291,456 bf16
    bf16*  qkv_y_bf = (bf16*)(ws + 3145728);     // 1,572,864 bf16
    float* catt     = ws + 3932160;              // 8,388,608 f (dead after rowsoft)
    bf16*  gated_bf = (bf16*)(ws + 3932160);     //   reuse
    bf16*  cval_bf  = (bf16*)(ws + 5242880);     //   reuse
    bf16*  x2y_bf   = (bf16*)(ws + 12320768);    // 8,388,608 bf16 (written at rowsoft)
    bf16*  x_bf     = x2y_bf;                    //   pre-QKV reuse
    bf16*  y_bf     = (bf16*)(ws + 13369344);    //   pre-QKV reuse
    bf16*  y2x_bf   = (bf16*)(ws + 16515072);    // 8,388,608 bf16
    bf16*  vTx_bf   = (bf16*)(ws + 20709376);    // 2,097,152 bf16
    bf16*  vTy_bf   = (bf16*)(ws + 21757952);    // 524,288 bf16
    float* cval     = ws + 22020096;             // 2,097,152 f
    float* psum_    = cval;                      //   pre-cval reuse (colpart)
    float* sval     = ws + 24117248;             // 2,097,152 f
    bf16*  qw_bf    = (bf16*)(ws + 26214400);    // 2,097,152 bf16 (dead after catt3)
    bf16*  sval_bf  = qw_bf;                     //   reuse
    bf16*  WT_x     = (bf16*)(ws + 27262976);    // 786,432 bf16
    bf16*  WT_y     = (bf16*)(ws + 27656192);
    bf16*  WT_gs    = (bf16*)(ws + 28049408);    // 262,144 bf16
    bf16*  WT_gc    = (bf16*)(ws + 28180480);
    bf16*  WT_p     = (bf16*)(ws + 28311552);
    float* catt1b   = ws + 28442624;             // 32,768 f
    float* catt2b   = ws + 28475392;             //  8,192 f
    float* colinv   = ws + 28483584;             //  8,192 f

    // 0: weight transposes + input converts
    transpose_w_kernel<<<dim3(24, 8), 256, 0, stream>>>(Wqkv_x, WT_x, C3_, C_);
    transpose_w_kernel<<<dim3(24, 8), 256, 0, stream>>>(Wqkv_y, WT_y, C3_, C_);
    transpose_w_kernel<<<dim3(8, 8), 256, 0, stream>>>(Wgs, WT_gs, C_, C_);
    transpose_w_kernel<<<dim3(8, 8), 256, 0, stream>>>(Wgc, WT_gc, C_, C_);
    transpose_w_kernel<<<dim3(8, 8), 256, 0, stream>>>(Wp, WT_p, C_, C_);
    tobf16_kernel<<<1024, 256, 0, stream>>>(x, x_bf);
    tobf16_kernel<<<256, 256, 0, stream>>>(y, y_bf);

    // 1-2: QKV projections (LDS-staged MFMA)
    gemm_staged_kernel<bf16><<<dim3(24, 32), 256, 0, stream>>>(x_bf, WT_x, bqkv_x, qkv_x_bf, C3_, C_);
    gemm_staged_kernel<bf16><<<dim3(24, 8), 256, 0, stream>>>(y_bf, WT_y, bqkv_y, qkv_y_bf, C3_, C_);

    // 3-5: attention logits
    catt12_kernel<<<128, 256, 0, stream>>>(qkv_x_bf, w4x, catt1b, T_);
    catt12_kernel<<<32, 256, 0, stream>>>(qkv_y_bf, w4y, catt2b, M_);
    qw_kernel<<<1024, 256, 0, stream>>>(qkv_x_bf, w4xy, qw_bf);
    catt3_kernel<<<dim3(4, 16, 32), 256, 0, stream>>>(qw_bf, qkv_y_bf, catt1b, catt2b, catt);

    // 6-7: softmaxes (col sums -> colinv; fused row pass -> x2y & y2x)
    colpart_kernel<<<dim3(16, 32), 256, 0, stream>>>(catt, psum_);
    colfin_kernel<<<32, 256, 0, stream>>>(psum_, colinv);
    rowsoft_kernel<<<8192, 256, 0, stream>>>(catt, colinv, x2y_bf, y2x_bf);

    // 8: V transposes
    vtrans_kernel<<<dim3(16, 32), 256, 0, stream>>>(qkv_x_bf, vTx_bf, T_);
    vtrans_kernel<<<dim3(4, 32), 256, 0, stream>>>(qkv_y_bf, vTy_bf, M_);

    // 9: cval = x + x2y@v_y + chain-attention (fused)
    flash2_kernel<0><<<dim3(16, 32), 256, 0, stream>>>(
        x2y_bf, y2x_bf, vTx_bf, vTy_bf, qkv_x_bf, x, 1.f / 16.f, cval, cval_bf);

    // 10: sval = causal self-attention
    flash2_kernel<1><<<dim3(16, 32), 256, 0, stream>>>(
        nullptr, nullptr, vTx_bf, nullptr, qkv_x_bf, nullptr, 0.125f, sval, sval_bf);

    // 11: fused gates -> gated bf16
    gatefuse_kernel<<<dim3(8, 32), 256, 0, stream>>>(
        sval_bf, cval_bf, WT_gs, WT_gc, bgs, bgc, cval, sval, gated_bf);

    // 12: out = gated @ Wp + bp
    gemm_staged_kernel<float><<<dim3(8, 32), 256, 0, stream>>>(
        gated_bf, WT_p, bp, (float*)d_out, C_, C_);
}

// Round 9
// 270.262 us; speedup vs baseline: 1.8534x; 1.1348x over previous
//
#include <hip/hip_runtime.h>
#include <hip/hip_bf16.h>

typedef __hip_bfloat16 bf16;
using f4 = __attribute__((ext_vector_type(4))) float;
using s8 = __attribute__((ext_vector_type(8))) short;
using s4 = __attribute__((ext_vector_type(4))) short;

__device__ __forceinline__ void storeOut(float* p, float v) { *p = v; }
__device__ __forceinline__ void storeOut(bf16* p, float v) { *p = __float2bfloat16(v); }
__device__ __forceinline__ short bfs(float x) { return __builtin_bit_cast(short, __float2bfloat16(x)); }

constexpr int B_ = 4, T_ = 1024, M_ = 256, C_ = 512, H_ = 8, HD_ = 64, C3_ = 1536;

#define MFMA16(a, b, c) __builtin_amdgcn_mfma_f32_16x16x32_bf16((a), (b), (c), 0, 0, 0)

// ---------------- prep: 5 weight transposes (fp32 KxN -> bf16 NxK) + 2 converts ----------------
__global__ __launch_bounds__(256) void prep_kernel(
    const float* __restrict__ Wqkv_x, const float* __restrict__ Wqkv_y,
    const float* __restrict__ Wgs, const float* __restrict__ Wgc, const float* __restrict__ Wp,
    const float* __restrict__ x, const float* __restrict__ y,
    bf16* __restrict__ WT_x, bf16* __restrict__ WT_y, bf16* __restrict__ WT_gs,
    bf16* __restrict__ WT_gc, bf16* __restrict__ WT_p,
    bf16* __restrict__ x_bf, bf16* __restrict__ y_bf)
{
    __shared__ float Ls[64][65];
    const int tid = threadIdx.x;
    const int bid = blockIdx.x;
    if (bid < 576) {
        const float* W; bf16* WT; int N, t;
        if (bid < 192)      { W = Wqkv_x; WT = WT_x;  N = C3_; t = bid; }
        else if (bid < 384) { W = Wqkv_y; WT = WT_y;  N = C3_; t = bid - 192; }
        else if (bid < 448) { W = Wgs;    WT = WT_gs; N = C_;  t = bid - 384; }
        else if (bid < 512) { W = Wgc;    WT = WT_gc; N = C_;  t = bid - 448; }
        else                { W = Wp;     WT = WT_p;  N = C_;  t = bid - 512; }
        const int K = C_;
        const int tw = N >> 6;
        const int n0 = (t % tw) * 64, k0 = (t / tw) * 64;
        for (int i = tid; i < 1024; i += 256) {
            int kr = i >> 4, ng = i & 15;
            float4 v = *(const float4*)&W[(size_t)(k0 + kr) * N + n0 + ng * 4];
            Ls[ng * 4 + 0][kr] = v.x; Ls[ng * 4 + 1][kr] = v.y;
            Ls[ng * 4 + 2][kr] = v.z; Ls[ng * 4 + 3][kr] = v.w;
        }
        __syncthreads();
        for (int i = tid; i < 512; i += 256) {
            int n = i >> 3, kg = i & 7;
            s8 r;
            #pragma unroll
            for (int j = 0; j < 8; ++j) r[j] = bfs(Ls[n][kg * 8 + j]);
            *(s8*)&WT[(size_t)(n0 + n) * K + k0 + kg * 8] = r;
        }
    } else if (bid < 1600) {
        int i = (bid - 576) * 2048 + tid * 8;
        s8 r;
        #pragma unroll
        for (int j = 0; j < 8; ++j) r[j] = bfs(x[i + j]);
        *(s8*)&x_bf[i] = r;
    } else {
        int i = (bid - 1600) * 2048 + tid * 8;
        s8 r;
        #pragma unroll
        for (int j = 0; j < 8; ++j) r[j] = bfs(y[i + j]);
        *(s8*)&y_bf[i] = r;
    }
}

// ---------------- qw = bf16(q_x * w4xy), layout (B*T, C) ----------------
__global__ __launch_bounds__(256) void qw_kernel(
    const bf16* __restrict__ qkv_x, const float* __restrict__ w4xy, bf16* __restrict__ qw)
{
    int o = (blockIdx.x * 256 + threadIdx.x) * 8;
    int row = o >> 9, c = o & 511;
    const bf16* src = qkv_x + (size_t)row * C3_ + c;
    s8 r;
    #pragma unroll
    for (int j = 0; j < 8; ++j) r[j] = bfs(__bfloat162float(src[j]) * w4xy[c + j]);
    *(s8*)&qw[o] = r;
}

// ---------------- LDS-staged MFMA GEMM: C = A(MxK bf16) @ WT^T + bias ----------------
template <typename OT>
__global__ __launch_bounds__(256) void gemm_staged_kernel(
    const bf16* __restrict__ A, const bf16* __restrict__ WT, const float* __restrict__ bias,
    OT* __restrict__ Cmat, int N, int K)
{
    __shared__ short Asb[128][72];
    __shared__ short Bsb[64][72];
    const int tid = threadIdx.x;
    const int wave = tid >> 6, lane = tid & 63;
    const int quad = lane >> 4, l16 = lane & 15;
    const int n0 = blockIdx.x * 64, m0 = blockIdx.y * 128;
    f4 acc[2][4];
    #pragma unroll
    for (int mt = 0; mt < 2; ++mt)
        #pragma unroll
        for (int nt = 0; nt < 4; ++nt) acc[mt][nt] = (f4)0.f;

    for (int k0 = 0; k0 < K; k0 += 64) {
        #pragma unroll
        for (int tl = 0; tl < 4; ++tl) {
            int g = tid + tl * 256, row = g >> 3, grp = g & 7;
            *(s8*)&Asb[row][grp * 8] = *(const s8*)&A[(size_t)(m0 + row) * K + k0 + grp * 8];
        }
        #pragma unroll
        for (int tl = 0; tl < 2; ++tl) {
            int g = tid + tl * 256, n = g >> 3, grp = g & 7;
            *(s8*)&Bsb[n][grp * 8] = *(const s8*)&WT[(size_t)(n0 + n) * K + k0 + grp * 8];
        }
        __syncthreads();
        #pragma unroll
        for (int ks = 0; ks < 2; ++ks) {
            s8 a0 = *(const s8*)&Asb[wave * 32 + l16][ks * 32 + quad * 8];
            s8 a1 = *(const s8*)&Asb[wave * 32 + 16 + l16][ks * 32 + quad * 8];
            #pragma unroll
            for (int nt = 0; nt < 4; ++nt) {
                s8 bv = *(const s8*)&Bsb[nt * 16 + l16][ks * 32 + quad * 8];
                acc[0][nt] = MFMA16(a0, bv, acc[0][nt]);
                acc[1][nt] = MFMA16(a1, bv, acc[1][nt]);
            }
        }
        __syncthreads();
    }
    #pragma unroll
    for (int mt = 0; mt < 2; ++mt)
        #pragma unroll
        for (int nt = 0; nt < 4; ++nt) {
            int col = n0 + nt * 16 + l16;
            float bb = bias[col];
            #pragma unroll
            for (int reg = 0; reg < 4; ++reg) {
                int row = m0 + wave * 32 + mt * 16 + quad * 4 + reg;
                storeOut(&Cmat[(size_t)row * N + col], acc[mt][nt][reg] + bb);
            }
        }
}

// ---------------- merged catt1/catt2 ----------------
__global__ __launch_bounds__(256) void catt12m_kernel(
    const bf16* __restrict__ qkv_x, const bf16* __restrict__ qkv_y,
    const float* __restrict__ w4x, const float* __restrict__ w4y,
    float* __restrict__ catt1b, float* __restrict__ catt2b)
{
    int i = blockIdx.x * 256 + threadIdx.x;   // 0..40959
    const bf16* row; const float* w; float* out; int oi;
    if (i < 32768) {
        int bh = i >> 10, t = i & 1023, b = bh >> 3, h = bh & 7;
        row = qkv_x + (size_t)(b * T_ + t) * C3_ + h * HD_;
        w = w4x + h * HD_; out = catt1b; oi = i;
    } else {
        int j = i - 32768;
        int bh = j >> 8, m = j & 255, b = bh >> 3, h = bh & 7;
        row = qkv_y + (size_t)(b * M_ + m) * C3_ + h * HD_;
        w = w4y + h * HD_; out = catt2b; oi = j;
    }
    float s = 0.f;
    #pragma unroll
    for (int d = 0; d < HD_; ++d) s = fmaf(__bfloat162float(row[d]), w[d], s);
    out[oi] = s;
}

// ---------------- catt = catt1 + catt2 + 0.125 * qw @ ky^T  [zero-LDS MFMA] ----------------
__global__ __launch_bounds__(256) void catt3_kernel(
    const bf16* __restrict__ qw, const bf16* __restrict__ qkv_y,
    const float* __restrict__ catt1, const float* __restrict__ catt2,
    float* __restrict__ catt)
{
    const int tid = threadIdx.x;
    const int wave = tid >> 6, lane = tid & 63;
    const int quad = lane >> 4, l16 = lane & 15;
    const int bh = blockIdx.z, b = bh >> 3, h = bh & 7;
    const int t0 = blockIdx.y * 64, m0 = blockIdx.x * 64;
    f4 sc[4];
    #pragma unroll
    for (int nt = 0; nt < 4; ++nt) sc[nt] = (f4)0.f;
    const bf16* ap = qw + (size_t)(b * T_ + t0 + wave * 16 + l16) * C_ + h * HD_ + quad * 8;
    const bf16* bp = qkv_y + (size_t)(b * M_ + m0 + l16) * C3_ + C_ + h * HD_ + quad * 8;
    #pragma unroll
    for (int k0 = 0; k0 < 64; k0 += 32) {
        s8 a = *(const s8*)(ap + k0);
        #pragma unroll
        for (int nt = 0; nt < 4; ++nt) {
            s8 bv = *(const s8*)(bp + (size_t)nt * 16 * C3_ + k0);
            sc[nt] = MFMA16(a, bv, sc[nt]);
        }
    }
    #pragma unroll
    for (int nt = 0; nt < 4; ++nt) {
        int m = m0 + nt * 16 + l16;
        float c2 = catt2[bh * M_ + m];
        #pragma unroll
        for (int reg = 0; reg < 4; ++reg) {
            int t = t0 + wave * 16 + quad * 4 + reg;
            catt[((size_t)bh * T_ + t) * M_ + m] =
                sc[nt][reg] * 0.125f + catt1[bh * T_ + t] + c2;
        }
    }
}

// ---------------- col softmax sums (no max — logits bounded) ----------------
__global__ __launch_bounds__(256) void colpart_kernel(
    const float* __restrict__ catt, float* __restrict__ psum)
{
    const int ch = blockIdx.x, bh = blockIdx.y, m = threadIdx.x;
    const float* p = catt + ((size_t)bh * T_ + ch * 64) * M_ + m;
    float s = 0.f;
    for (int t = 0; t < 64; ++t) s += __expf(p[t * M_]);
    psum[(bh * 16 + ch) * M_ + m] = s;
}

__global__ __launch_bounds__(256) void colfin_kernel(
    const float* __restrict__ psum, float* __restrict__ colinv)
{
    const int bh = blockIdx.x, m = threadIdx.x;
    float s = 0.f;
    #pragma unroll
    for (int ch = 0; ch < 16; ++ch) s += psum[(bh * 16 + ch) * M_ + m];
    colinv[bh * M_ + m] = 1.f / s;
}

// ---------------- fused row softmax -> x2y bf16 AND y2x bf16 ----------------
__global__ __launch_bounds__(256) void rowsoft_kernel(
    const float* __restrict__ catt, const float* __restrict__ colinv,
    bf16* __restrict__ x2y, bf16* __restrict__ y2x)
{
    const int wave = threadIdx.x >> 6, lane = threadIdx.x & 63;
    const int row = blockIdx.x * 4 + wave;
    const int bh = row >> 10;
    const float* p = catt + (size_t)row * M_;
    float e[4];
    float s = 0.f;
    #pragma unroll
    for (int j = 0; j < 4; ++j) { e[j] = __expf(p[j * 64 + lane]); s += e[j]; }
    for (int off = 1; off < 64; off <<= 1) s += __shfl_xor(s, off);
    float inv = 1.f / s;
    #pragma unroll
    for (int j = 0; j < 4; ++j) {
        int m = j * 64 + lane;
        x2y[(size_t)row * M_ + m] = __float2bfloat16(e[j] * inv);
        y2x[(size_t)row * M_ + m] = __float2bfloat16(e[j] * colinv[bh * M_ + m]);
    }
}

// ---------------- merged V transposes: v_x -> vTx, v_y -> vTy ----------------
__global__ __launch_bounds__(256) void vtransm_kernel(
    const bf16* __restrict__ qkv_x, const bf16* __restrict__ qkv_y,
    bf16* __restrict__ vTx, bf16* __restrict__ vTy)
{
    __shared__ short Ls[64][68];
    const int tid = threadIdx.x;
    int bid = blockIdx.x;
    const bf16* qkv; bf16* vT; int Nrows, bh, t0;
    if (bid < 512) { qkv = qkv_x; vT = vTx; Nrows = T_; bh = bid >> 4; t0 = (bid & 15) * 64; }
    else { bid -= 512; qkv = qkv_y; vT = vTy; Nrows = M_; bh = bid >> 2; t0 = (bid & 3) * 64; }
    const int b = bh >> 3, h = bh & 7;
    for (int i = tid; i < 4096; i += 256) {
        int tl = i >> 6, d = i & 63;
        Ls[d][tl] = __builtin_bit_cast(short,
            qkv[(size_t)(b * Nrows + t0 + tl) * C3_ + 2 * C_ + h * HD_ + d]);
    }
    __syncthreads();
    for (int i = tid; i < 4096; i += 256) {
        int d = i >> 6, tl = i & 63;
        vT[((size_t)bh * 64 + d) * Nrows + t0 + tl] = __builtin_bit_cast(bf16, Ls[d][tl]);
    }
}

// ---------------- merged flash: chain + self attention + fused cval ----------------
// Shares V=v_x tile between both attentions; single-buffered LDS (59.5 KB -> 2 blocks/CU);
// VGPR prefetch + 2 barriers/tile; no-max softmax (logits bounded, l = plain sum);
// complementary-jt swizzle so co-resident blocks have jt and 15-jt (uniform 17 tiles/CU);
// Ps row stride 68 shorts -> conflict-free b16 writes, A-frag via 2x aligned b64.
__global__ __launch_bounds__(256) void flash3_kernel(
    const bf16* __restrict__ x2y, const bf16* __restrict__ y2x,
    const bf16* __restrict__ vTx, const bf16* __restrict__ vTy,
    const bf16* __restrict__ qkv_x, const float* __restrict__ x,
    float* __restrict__ cval, bf16* __restrict__ cval_bf,
    float* __restrict__ sval, bf16* __restrict__ sval_bf)
{
    __shared__ short Kc[64][264];     // chain K (64 keys x 256)
    __shared__ short Ksf[64][72];     // self K (64 keys x 64)
    __shared__ short Vb[64][72];      // V^T (64 d x 64 s)
    __shared__ short Ps[4][16][68];   // wave-private P
    const int tid = threadIdx.x;
    const int wave = tid >> 6, lane = tid & 63;
    const int quad = lane >> 4, l16 = lane & 15;
    const int bh = blockIdx.y, b = bh >> 3, h = bh & 7;
    const int jt = (blockIdx.y < 16) ? (int)blockIdx.x : 15 - (int)blockIdx.x;
    const int t0 = jt * 64;
    const int nst = jt + 1;

    // Q fragments in registers
    s8 qc[8], qs[2];
    {
        const bf16* qp = x2y + (size_t)(bh * T_ + t0 + wave * 16 + l16) * M_ + quad * 8;
        #pragma unroll
        for (int f = 0; f < 8; ++f) qc[f] = *(const s8*)(qp + f * 32);
        const bf16* qsp = qkv_x + (size_t)(b * T_ + t0 + wave * 16 + l16) * C3_ + h * HD_ + quad * 8;
        qs[0] = *(const s8*)qsp;
        qs[1] = *(const s8*)(qsp + 32);
    }

    // fused cval: ocv = x2y(regs) @ vTy (once per block; vTy is L2-resident)
    f4 ocv[4];
    #pragma unroll
    for (int dt = 0; dt < 4; ++dt) ocv[dt] = (f4)0.f;
    {
        const bf16* vb = vTy + (size_t)(bh * 64 + l16) * M_ + quad * 8;
        #pragma unroll
        for (int f = 0; f < 8; ++f)
            #pragma unroll
            for (int dt = 0; dt < 4; ++dt) {
                s8 bv = *(const s8*)(vb + (size_t)dt * 16 * M_ + f * 32);
                ocv[dt] = MFMA16(qc[f], bv, ocv[dt]);
            }
    }

    f4 oc[4], os_[4];
    float lc[4] = {0.f, 0.f, 0.f, 0.f}, ls_[4] = {0.f, 0.f, 0.f, 0.f};
    #pragma unroll
    for (int dt = 0; dt < 4; ++dt) { oc[dt] = (f4)0.f; os_[dt] = (f4)0.f; }

    // prologue: stage tile 0
    #pragma unroll
    for (int tl = 0; tl < 8; ++tl) {
        int g = tid + tl * 256, row = g >> 5, grp = g & 31;
        *(s8*)&Kc[row][grp * 8] = *(const s8*)&y2x[(size_t)(bh * T_ + row) * M_ + grp * 8];
    }
    #pragma unroll
    for (int tl = 0; tl < 2; ++tl) {
        int g = tid + tl * 256, row = g >> 3, grp = g & 7;
        *(s8*)&Ksf[row][grp * 8] =
            *(const s8*)&qkv_x[(size_t)(b * T_ + row) * C3_ + C_ + h * HD_ + grp * 8];
        *(s8*)&Vb[row][grp * 8] = *(const s8*)&vTx[(size_t)(bh * 64 + row) * T_ + grp * 8];
    }
    __syncthreads();

    for (int st = 0; st < nst; ++st) {
        const int s0 = st * 64;
        const bool pf = (st + 1) < nst;
        s8 kcp[8], ksp[2], vp[2];
        if (pf) {
            const int sn = s0 + 64;
            #pragma unroll
            for (int tl = 0; tl < 8; ++tl) {
                int g = tid + tl * 256, row = g >> 5, grp = g & 31;
                kcp[tl] = *(const s8*)&y2x[(size_t)(bh * T_ + sn + row) * M_ + grp * 8];
            }
            #pragma unroll
            for (int tl = 0; tl < 2; ++tl) {
                int g = tid + tl * 256, row = g >> 3, grp = g & 7;
                ksp[tl] = *(const s8*)&qkv_x[(size_t)(b * T_ + sn + row) * C3_ + C_ + h * HD_ + grp * 8];
                vp[tl] = *(const s8*)&vTx[(size_t)(bh * 64 + row) * T_ + sn + grp * 8];
            }
        }
        // chain QK^T
        f4 sc[4];
        #pragma unroll
        for (int nt = 0; nt < 4; ++nt) sc[nt] = (f4)0.f;
        #pragma unroll
        for (int f = 0; f < 8; ++f)
            #pragma unroll
            for (int nt = 0; nt < 4; ++nt) {
                s8 bv = *(const s8*)&Kc[nt * 16 + l16][f * 32 + quad * 8];
                sc[nt] = MFMA16(qc[f], bv, sc[nt]);
            }
        // self QK^T
        f4 ss[4];
        #pragma unroll
        for (int nt = 0; nt < 4; ++nt) ss[nt] = (f4)0.f;
        #pragma unroll
        for (int f = 0; f < 2; ++f)
            #pragma unroll
            for (int nt = 0; nt < 4; ++nt) {
                s8 bv = *(const s8*)&Ksf[nt * 16 + l16][f * 32 + quad * 8];
                ss[nt] = MFMA16(qs[f], bv, ss[nt]);
            }
        // chain softmax -> Ps, PV
        #pragma unroll
        for (int reg = 0; reg < 4; ++reg) {
            const int t_g = t0 + wave * 16 + quad * 4 + reg;
            #pragma unroll
            for (int nt = 0; nt < 4; ++nt) {
                float p = (s0 + nt * 16 + l16 <= t_g) ? __expf(sc[nt][reg] * (1.f / 16.f)) : 0.f;
                lc[reg] += p;
                Ps[wave][quad * 4 + reg][nt * 16 + l16] = bfs(p);
            }
        }
        #pragma unroll
        for (int ks = 0; ks < 2; ++ks) {
            const short* pp = &Ps[wave][l16][ks * 32 + quad * 8];
            s4 alo = *(const s4*)pp;
            s4 ahi = *(const s4*)(pp + 4);
            s8 a;
            a[0] = alo[0]; a[1] = alo[1]; a[2] = alo[2]; a[3] = alo[3];
            a[4] = ahi[0]; a[5] = ahi[1]; a[6] = ahi[2]; a[7] = ahi[3];
            #pragma unroll
            for (int dt = 0; dt < 4; ++dt) {
                s8 bv = *(const s8*)&Vb[dt * 16 + l16][ks * 32 + quad * 8];
                oc[dt] = MFMA16(a, bv, oc[dt]);
            }
        }
        // self softmax -> Ps (overwrite; wave-private ordering), PV
        #pragma unroll
        for (int reg = 0; reg < 4; ++reg) {
            const int t_g = t0 + wave * 16 + quad * 4 + reg;
            #pragma unroll
            for (int nt = 0; nt < 4; ++nt) {
                float p = (s0 + nt * 16 + l16 <= t_g) ? __expf(ss[nt][reg] * 0.125f) : 0.f;
                ls_[reg] += p;
                Ps[wave][quad * 4 + reg][nt * 16 + l16] = bfs(p);
            }
        }
        #pragma unroll
        for (int ks = 0; ks < 2; ++ks) {
            const short* pp = &Ps[wave][l16][ks * 32 + quad * 8];
            s4 alo = *(const s4*)pp;
            s4 ahi = *(const s4*)(pp + 4);
            s8 a;
            a[0] = alo[0]; a[1] = alo[1]; a[2] = alo[2]; a[3] = alo[3];
            a[4] = ahi[0]; a[5] = ahi[1]; a[6] = ahi[2]; a[7] = ahi[3];
            #pragma unroll
            for (int dt = 0; dt < 4; ++dt) {
                s8 bv = *(const s8*)&Vb[dt * 16 + l16][ks * 32 + quad * 8];
                os_[dt] = MFMA16(a, bv, os_[dt]);
            }
        }
        __syncthreads();   // all waves done reading Kc/Ksf/Vb
        if (pf) {
            #pragma unroll
            for (int tl = 0; tl < 8; ++tl) {
                int g = tid + tl * 256, row = g >> 5, grp = g & 31;
                *(s8*)&Kc[row][grp * 8] = kcp[tl];
            }
            #pragma unroll
            for (int tl = 0; tl < 2; ++tl) {
                int g = tid + tl * 256, row = g >> 3, grp = g & 7;
                *(s8*)&Ksf[row][grp * 8] = ksp[tl];
                *(s8*)&Vb[row][grp * 8] = vp[tl];
            }
        }
        __syncthreads();   // new tile visible
    }

    #pragma unroll
    for (int reg = 0; reg < 4; ++reg) {
        float l1 = lc[reg], l2 = ls_[reg];
        l1 += __shfl_xor(l1, 1); l1 += __shfl_xor(l1, 2);
        l1 += __shfl_xor(l1, 4); l1 += __shfl_xor(l1, 8);
        l2 += __shfl_xor(l2, 1); l2 += __shfl_xor(l2, 2);
        l2 += __shfl_xor(l2, 4); l2 += __shfl_xor(l2, 8);
        const float i1 = 1.f / l1, i2 = 1.f / l2;
        const int t = t0 + wave * 16 + quad * 4 + reg;
        #pragma unroll
        for (int dt = 0; dt < 4; ++dt) {
            size_t idx = (size_t)(b * T_ + t) * C_ + h * HD_ + dt * 16 + l16;
            float cv = ocv[dt][reg] + oc[dt][reg] * i1 + x[idx];
            cval[idx] = cv;
            cval_bf[idx] = __float2bfloat16(cv);
            float sv = os_[dt][reg] * i2;
            sval[idx] = sv;
            sval_bf[idx] = __float2bfloat16(sv);
        }
    }
}

// ---------------- fused dual gate GEMM + sigmoid + combine -> gated bf16 ----------------
__global__ __launch_bounds__(256) void gatefuse_kernel(
    const bf16* __restrict__ svalb, const bf16* __restrict__ cvalb,
    const bf16* __restrict__ WTgs, const bf16* __restrict__ WTgc,
    const float* __restrict__ bgs, const float* __restrict__ bgc,
    const float* __restrict__ cval, const float* __restrict__ sval,
    bf16* __restrict__ gated)
{
    __shared__ short Sb[128][72], Cb[128][72], W1b[64][72], W2b[64][72];
    const int tid = threadIdx.x;
    const int wave = tid >> 6, lane = tid & 63;
    const int quad = lane >> 4, l16 = lane & 15;
    const int n0 = blockIdx.x * 64, m0 = blockIdx.y * 128;
    f4 aS[2][4], aC[2][4];
    #pragma unroll
    for (int mt = 0; mt < 2; ++mt)
        #pragma unroll
        for (int nt = 0; nt < 4; ++nt) { aS[mt][nt] = (f4)0.f; aC[mt][nt] = (f4)0.f; }

    for (int k0 = 0; k0 < C_; k0 += 64) {
        #pragma unroll
        for (int tl = 0; tl < 4; ++tl) {
            int g = tid + tl * 256, row = g >> 3, grp = g & 7;
            *(s8*)&Sb[row][grp * 8] = *(const s8*)&svalb[(size_t)(m0 + row) * C_ + k0 + grp * 8];
            *(s8*)&Cb[row][grp * 8] = *(const s8*)&cvalb[(size_t)(m0 + row) * C_ + k0 + grp * 8];
        }
        #pragma unroll
        for (int tl = 0; tl < 2; ++tl) {
            int g = tid + tl * 256, n = g >> 3, grp = g & 7;
            *(s8*)&W1b[n][grp * 8] = *(const s8*)&WTgs[(size_t)(n0 + n) * C_ + k0 + grp * 8];
            *(s8*)&W2b[n][grp * 8] = *(const s8*)&WTgc[(size_t)(n0 + n) * C_ + k0 + grp * 8];
        }
        __syncthreads();
        #pragma unroll
        for (int ks = 0; ks < 2; ++ks) {
            s8 s0f = *(const s8*)&Sb[wave * 32 + l16][ks * 32 + quad * 8];
            s8 s1f = *(const s8*)&Sb[wave * 32 + 16 + l16][ks * 32 + quad * 8];
            s8 c0f = *(const s8*)&Cb[wave * 32 + l16][ks * 32 + quad * 8];
            s8 c1f = *(const s8*)&Cb[wave * 32 + 16 + l16][ks * 32 + quad * 8];
            #pragma unroll
            for (int nt = 0; nt < 4; ++nt) {
                s8 w1 = *(const s8*)&W1b[nt * 16 + l16][ks * 32 + quad * 8];
                s8 w2 = *(const s8*)&W2b[nt * 16 + l16][ks * 32 + quad * 8];
                aS[0][nt] = MFMA16(s0f, w1, aS[0][nt]);
                aS[1][nt] = MFMA16(s1f, w1, aS[1][nt]);
                aC[0][nt] = MFMA16(c0f, w2, aC[0][nt]);
                aC[1][nt] = MFMA16(c1f, w2, aC[1][nt]);
            }
        }
        __syncthreads();
    }
    #pragma unroll
    for (int mt = 0; mt < 2; ++mt)
        #pragma unroll
        for (int nt = 0; nt < 4; ++nt) {
            int col = n0 + nt * 16 + l16;
            float b1 = bgs[col], b2 = bgc[col];
            #pragma unroll
            for (int reg = 0; reg < 4; ++reg) {
                int row = m0 + wave * 32 + mt * 16 + quad * 4 + reg;
                size_t idx = (size_t)row * C_ + col;
                float gs = 1.f / (1.f + __expf(-(aS[mt][nt][reg] + b1)));
                float gc = 1.f / (1.f + __expf(-(aC[mt][nt][reg] + b2)));
                gated[idx] = __float2bfloat16(gs * cval[idx] + gc * sval[idx]);
            }
        }
}

extern "C" void kernel_launch(void* const* d_in, const int* in_sizes, int n_in,
                              void* d_out, int out_size, void* d_ws, size_t ws_size,
                              hipStream_t stream)
{
    const float* x      = (const float*)d_in[0];
    const float* y      = (const float*)d_in[1];
    // d_in[2]: attn_x_mask — structurally causal tril, computed inline
    const float* Wqkv_x = (const float*)d_in[3];
    const float* bqkv_x = (const float*)d_in[4];
    const float* Wqkv_y = (const float*)d_in[5];
    const float* bqkv_y = (const float*)d_in[6];
    const float* w4x    = (const float*)d_in[7];
    const float* w4y    = (const float*)d_in[8];
    const float* w4xy   = (const float*)d_in[9];
    const float* Wgs    = (const float*)d_in[10];
    const float* bgs    = (const float*)d_in[11];
    const float* Wgc    = (const float*)d_in[12];
    const float* bgc    = (const float*)d_in[13];
    const float* Wp     = (const float*)d_in[14];
    const float* bp     = (const float*)d_in[15];

    // Workspace (f-word offsets; layout proven in R8)
    float* ws = (float*)d_ws;
    bf16*  qkv_x_bf = (bf16*)(ws + 0);           // 6,291,456 bf16
    bf16*  qkv_y_bf = (bf16*)(ws + 3145728);     // 1,572,864 bf16
    float* catt     = ws + 3932160;              // 8,388,608 f (dead after rowsoft)
    bf16*  gated_bf = (bf16*)(ws + 3932160);     //   reuse
    bf16*  cval_bf  = (bf16*)(ws + 5242880);     //   reuse
    bf16*  x2y_bf   = (bf16*)(ws + 12320768);    // 8,388,608 bf16 (written at rowsoft)
    bf16*  x_bf     = x2y_bf;                    //   pre-QKV reuse
    bf16*  y_bf     = (bf16*)(ws + 13369344);    //   pre-QKV reuse
    bf16*  y2x_bf   = (bf16*)(ws + 16515072);    // 8,388,608 bf16
    bf16*  vTx_bf   = (bf16*)(ws + 20709376);    // 2,097,152 bf16
    bf16*  vTy_bf   = (bf16*)(ws + 21757952);    // 524,288 bf16
    float* cval     = ws + 22020096;             // 2,097,152 f
    float* psum_    = cval;                      //   pre-cval reuse (colpart)
    float* sval     = ws + 24117248;             // 2,097,152 f
    bf16*  qw_bf    = (bf16*)(ws + 26214400);    // 2,097,152 bf16 (dead after catt3)
    bf16*  sval_bf  = qw_bf;                     //   reuse
    bf16*  WT_x     = (bf16*)(ws + 27262976);    // 786,432 bf16
    bf16*  WT_y     = (bf16*)(ws + 27656192);
    bf16*  WT_gs    = (bf16*)(ws + 28049408);    // 262,144 bf16
    bf16*  WT_gc    = (bf16*)(ws + 28180480);
    bf16*  WT_p     = (bf16*)(ws + 28311552);
    float* catt1b   = ws + 28442624;             // 32,768 f
    float* catt2b   = ws + 28475392;             //  8,192 f
    float* colinv   = ws + 28483584;             //  8,192 f

    // 0: one prep dispatch (5 transposes + 2 converts)
    prep_kernel<<<1856, 256, 0, stream>>>(
        Wqkv_x, Wqkv_y, Wgs, Wgc, Wp, x, y,
        WT_x, WT_y, WT_gs, WT_gc, WT_p, x_bf, y_bf);

    // 1-2: QKV projections
    gemm_staged_kernel<bf16><<<dim3(24, 32), 256, 0, stream>>>(x_bf, WT_x, bqkv_x, qkv_x_bf, C3_, C_);
    gemm_staged_kernel<bf16><<<dim3(24, 8), 256, 0, stream>>>(y_bf, WT_y, bqkv_y, qkv_y_bf, C3_, C_);

    // 3-5: attention logits
    catt12m_kernel<<<160, 256, 0, stream>>>(qkv_x_bf, qkv_y_bf, w4x, w4y, catt1b, catt2b);
    qw_kernel<<<1024, 256, 0, stream>>>(qkv_x_bf, w4xy, qw_bf);
    catt3_kernel<<<dim3(4, 16, 32), 256, 0, stream>>>(qw_bf, qkv_y_bf, catt1b, catt2b, catt);

    // 6-7: softmaxes
    colpart_kernel<<<dim3(16, 32), 256, 0, stream>>>(catt, psum_);
    colfin_kernel<<<32, 256, 0, stream>>>(psum_, colinv);
    rowsoft_kernel<<<8192, 256, 0, stream>>>(catt, colinv, x2y_bf, y2x_bf);

    // 8: V transposes (one dispatch)
    vtransm_kernel<<<640, 256, 0, stream>>>(qkv_x_bf, qkv_y_bf, vTx_bf, vTy_bf);

    // 9: merged flash — cval = x + x2y@v_y + chain-attn; sval = self-attn
    flash3_kernel<<<dim3(16, 32), 256, 0, stream>>>(
        x2y_bf, y2x_bf, vTx_bf, vTy_bf, qkv_x_bf, x, cval, cval_bf, sval, sval_bf);

    // 10: fused gates -> gated bf16
    gatefuse_kernel<<<dim3(8, 32), 256, 0, stream>>>(
        sval_bf, cval_bf, WT_gs, WT_gc, bgs, bgc, cval, sval, gated_bf);

    // 11: out = gated @ Wp + bp
    gemm_staged_kernel<float><<<dim3(8, 32), 256, 0, stream>>>(
        gated_bf, WT_p, bp, (float*)d_out, C_, C_);
}